// Round 1
// baseline (1329.316 us; speedup 1.0000x reference)
//
#include <hip/hip_runtime.h>

#define LTOT 5440
#define NTOK 21760   // B*L = 4*5440

typedef float  f32x4  __attribute__((ext_vector_type(4)));
typedef short  short8 __attribute__((ext_vector_type(8)));

__device__ __forceinline__ unsigned short f2bf(float f) {
  unsigned int u = __float_as_uint(f);
  u += 0x7FFF + ((u >> 16) & 1);          // RNE
  return (unsigned short)(u >> 16);
}

// ---------------------------------------------------------------------------
// Weight convert+transpose: all six weight kinds, all 6 layers -> bf16 [N][K]
// dst layout per layer (elements): off[256][256]@0, attn[128][256]@65536,
// val[256][256]@98304, out[256][256]@163840, ff1[1024][256]@229376,
// ff2[256][1024]@491520 ; per-layer stride 753664.
// ---------------------------------------------------------------------------
__global__ void wconv(const float* __restrict__ w_off, const float* __restrict__ w_attn,
                      const float* __restrict__ w_val, const float* __restrict__ w_out,
                      const float* __restrict__ w_ff1, const float* __restrict__ w_ff2,
                      unsigned short* __restrict__ dst) {
  int tid = blockIdx.x * 256 + threadIdx.x;
  const int PER = 753664;
  if (tid >= 6 * PER) return;
  int layer = tid / PER;
  int rem = tid - layer * PER;
  int base, K, N;
  const float* src;
  if (rem < 65536)       { base = 0;      K = 256;  N = 256;  src = w_off; }
  else if (rem < 98304)  { base = 65536;  K = 256;  N = 128;  src = w_attn; }
  else if (rem < 163840) { base = 98304;  K = 256;  N = 256;  src = w_val; }
  else if (rem < 229376) { base = 163840; K = 256;  N = 256;  src = w_out; }
  else if (rem < 491520) { base = 229376; K = 256;  N = 1024; src = w_ff1; }
  else                   { base = 491520; K = 1024; N = 256;  src = w_ff2; }
  int local = rem - base;
  int n = local / K, k = local - n * K;
  dst[tid] = f2bf(src[(size_t)layer * K * N + (size_t)k * N + n]);
}

// x = src (f32 master copy) + bf16 shadow
__global__ void prep(const float* __restrict__ src, float* __restrict__ x,
                     unsigned short* __restrict__ xb) {
  int i = blockIdx.x * 256 + threadIdx.x;   // float4 index, NTOK*64 total
  float4 s = ((const float4*)src)[i];
  ((float4*)x)[i] = s;
  ushort4 o;
  o.x = f2bf(s.x); o.y = f2bf(s.y); o.z = f2bf(s.z); o.w = f2bf(s.w);
  ((ushort4*)xb)[i] = o;
}

// q = bf16(x + pos + level_embed[lev(token)])
__global__ void qadd(const float* __restrict__ x, const float* __restrict__ pos,
                     const float* __restrict__ lev_emb, unsigned short* __restrict__ qb) {
  int i = blockIdx.x * 256 + threadIdx.x;   // float4 index
  int d4 = i & 63;
  int tok = (i >> 6) % LTOT;
  int lev = (tok < 64) ? 0 : (tok < 320) ? 1 : (tok < 1344) ? 2 : 3;
  float4 xv = ((const float4*)x)[i];
  float4 pv = ((const float4*)pos)[i];
  float4 lv = ((const float4*)lev_emb)[lev * 64 + d4];
  ushort4 o;
  o.x = f2bf(xv.x + pv.x + lv.x);
  o.y = f2bf(xv.y + pv.y + lv.y);
  o.z = f2bf(xv.z + pv.z + lv.z);
  o.w = f2bf(xv.w + pv.w + lv.w);
  ((ushort4*)qb)[i] = o;
}

// ---------------------------------------------------------------------------
// bf16 MFMA GEMM, C = A[M][K] * Wt[N][K]^T + bias.  TN layout, 128x128 tile,
// BK=64, 4 waves (2x2), 16x16x32 fragments. M,N,K all multiples of tile dims.
// ---------------------------------------------------------------------------
template<bool RELU, bool OBF16>
__global__ __launch_bounds__(256) void gemm_tn(
    const unsigned short* __restrict__ A, const unsigned short* __restrict__ Wt,
    const float* __restrict__ bias, void* __restrict__ Cout,
    int M, int N, int K) {
  __shared__ __align__(16) unsigned short a_lds[128 * 64];
  __shared__ __align__(16) unsigned short b_lds[128 * 64];
  int m0 = blockIdx.x * 128;
  int n0 = blockIdx.y * 128;
  int t = threadIdx.x;
  int w = t >> 6, l = t & 63;
  int wr = (w >> 1) * 64, wc = (w & 1) * 64;
  int lr = l & 15, lk = (l >> 4) * 8;

  f32x4 acc[4][4] = {};

  for (int k0 = 0; k0 < K; k0 += 64) {
#pragma unroll
    for (int i = 0; i < 4; ++i) {
      int c = i * 256 + t;
      int row = c >> 3, off8 = (c & 7) * 8;
      const unsigned short* gp = A + (size_t)(m0 + row) * K + k0 + off8;
      __builtin_amdgcn_global_load_lds(
          (const __attribute__((address_space(1))) void*)gp,
          (__attribute__((address_space(3))) void*)(a_lds + c * 8), 16, 0, 0);
    }
#pragma unroll
    for (int i = 0; i < 4; ++i) {
      int c = i * 256 + t;
      int row = c >> 3, off8 = (c & 7) * 8;
      const unsigned short* gp = Wt + (size_t)(n0 + row) * K + k0 + off8;
      __builtin_amdgcn_global_load_lds(
          (const __attribute__((address_space(1))) void*)gp,
          (__attribute__((address_space(3))) void*)(b_lds + c * 8), 16, 0, 0);
    }
    __syncthreads();
#pragma unroll
    for (int kk = 0; kk < 64; kk += 32) {
      short8 af[4], bfr[4];
#pragma unroll
      for (int m = 0; m < 4; ++m)
        af[m] = *(const short8*)(a_lds + (wr + m * 16 + lr) * 64 + kk + lk);
#pragma unroll
      for (int n = 0; n < 4; ++n)
        bfr[n] = *(const short8*)(b_lds + (wc + n * 16 + lr) * 64 + kk + lk);
#pragma unroll
      for (int m = 0; m < 4; ++m)
#pragma unroll
        for (int n = 0; n < 4; ++n)
          acc[m][n] = __builtin_amdgcn_mfma_f32_16x16x32_bf16(af[m], bfr[n], acc[m][n], 0, 0, 0);
    }
    __syncthreads();
  }

  int rb = (l >> 4) * 4;
#pragma unroll
  for (int n = 0; n < 4; ++n) {
    int col = n0 + wc + n * 16 + lr;
    float bv = bias[col];
#pragma unroll
    for (int m = 0; m < 4; ++m) {
#pragma unroll
      for (int r = 0; r < 4; ++r) {
        int row = m0 + wr + m * 16 + rb + r;
        float v = acc[m][n][r] + bv;
        if (RELU) v = fmaxf(v, 0.0f);
        if (OBF16) ((unsigned short*)Cout)[(size_t)row * N + col] = f2bf(v);
        else       ((float*)Cout)[(size_t)row * N + col] = v;
      }
    }
  }
}

// softmax over groups of 16 (one thread per (b,l,h) row); in place
__global__ void softmax16(float* __restrict__ a) {
  int row = blockIdx.x * 256 + threadIdx.x;   // NTOK*8 rows
  float4* p = ((float4*)a) + (size_t)row * 4;
  float4 v0 = p[0], v1 = p[1], v2 = p[2], v3 = p[3];
  float vv[16] = {v0.x, v0.y, v0.z, v0.w, v1.x, v1.y, v1.z, v1.w,
                  v2.x, v2.y, v2.z, v2.w, v3.x, v3.y, v3.z, v3.w};
  float m = vv[0];
#pragma unroll
  for (int i = 1; i < 16; ++i) m = fmaxf(m, vv[i]);
  float s = 0.0f;
#pragma unroll
  for (int i = 0; i < 16; ++i) { vv[i] = __expf(vv[i] - m); s += vv[i]; }
  float inv = 1.0f / s;
#pragma unroll
  for (int i = 0; i < 16; ++i) vv[i] *= inv;
  p[0] = make_float4(vv[0], vv[1], vv[2], vv[3]);
  p[1] = make_float4(vv[4], vv[5], vv[6], vv[7]);
  p[2] = make_float4(vv[8], vv[9], vv[10], vv[11]);
  p[3] = make_float4(vv[12], vv[13], vv[14], vv[15]);
}

// ---------------------------------------------------------------------------
// deformable sampling: one block per (b,l) token.
// phase1 (t<128 = h*16+lev*4+pt): corner indices + attn-premultiplied weights
// phase2 (all 256 = h*32+dh): gather v and reduce over 16 samples x 4 corners
// ---------------------------------------------------------------------------
__global__ __launch_bounds__(256) void ms_sample(
    const float* __restrict__ offp, const float* __restrict__ attnp,
    const float* __restrict__ v, unsigned short* __restrict__ samp) {
  __shared__ int   sIdx[128 * 4];
  __shared__ float sWt[128 * 4];
  int bl = blockIdx.x;
  int t = threadIdx.x;
  int l = bl % LTOT;
  int bbase = (bl - l) * 256;              // b*L*256
  if (t < 128) {
    int lev = (t >> 2) & 3;
    int lev_q = (l < 64) ? 0 : (l < 320) ? 1 : (l < 1344) ? 2 : 3;
    int start_q = (lev_q == 0) ? 0 : (lev_q == 1) ? 64 : (lev_q == 2) ? 320 : 1344;
    int shq = lev_q + 3;
    int r = l - start_q;
    int Wq = 1 << shq;
    int iy = r >> shq, ix = r & (Wq - 1);
    float invWq = 1.0f / (float)Wq;
    float refx = ((float)ix + 0.5f) * invWq;
    float refy = ((float)iy + 0.5f) * invWq;
    int iW = 8 << lev;
    float Wl = (float)iW;
    int start_l = (lev == 0) ? 0 : (lev == 1) ? 64 : (lev == 2) ? 320 : 1344;
    float ox = offp[bl * 256 + 2 * t];
    float oy = offp[bl * 256 + 2 * t + 1];
    float aw = attnp[bl * 128 + t];
    // (ref + off/W)*W - 0.5 == ref*W + off - 0.5
    float gx = refx * Wl + ox - 0.5f;
    float gy = refy * Wl + oy - 0.5f;
    float flx = floorf(gx), fly = floorf(gy);
    int x0 = (int)flx, y0 = (int)fly;
    float fx = gx - flx, fy = gy - fly;
#pragma unroll
    for (int c = 0; c < 4; ++c) {
      int cx = x0 + (c & 1);
      int cy = y0 + (c >> 1);
      int inb = (cx >= 0) && (cx < iW) && (cy >= 0) && (cy < iW);
      int cxc = cx < 0 ? 0 : (cx > iW - 1 ? iW - 1 : cx);
      int cyc = cy < 0 ? 0 : (cy > iW - 1 ? iW - 1 : cy);
      float wx = (c & 1) ? fx : 1.0f - fx;
      float wy = (c & 2) ? fy : 1.0f - fy;
      sIdx[t * 4 + c] = (start_l + cyc * iW + cxc) * 256;
      sWt[t * 4 + c] = inb ? aw * wx * wy : 0.0f;
    }
  }
  __syncthreads();
  int h = t >> 5;
  int sbase = h * 64;                      // h*16 samples * 4 corners
  float acc = 0.0f;
#pragma unroll 4
  for (int s = 0; s < 16; ++s) {
#pragma unroll
    for (int c = 0; c < 4; ++c) {
      float wgt = sWt[sbase + s * 4 + c];
      int idx = sIdx[sbase + s * 4 + c];
      acc = fmaf(wgt, v[bbase + idx + t], acc);   // channel = h*32+dh = t
    }
  }
  samp[(size_t)bl * 256 + t] = f2bf(acc);
}

// x' = LN(x + y); writes f32 (xout) + bf16 shadow. one wave per 256-row.
__global__ __launch_bounds__(256) void ln_fused(
    const float* __restrict__ xin, const float* __restrict__ yin,
    const float* __restrict__ g, const float* __restrict__ bb,
    float* __restrict__ xout, unsigned short* __restrict__ xbout) {
  int row = blockIdx.x * 4 + (threadIdx.x >> 6);
  int lane = threadIdx.x & 63;
  size_t base = (size_t)row * 64 + lane;   // float4 units
  float4 xv = ((const float4*)xin)[base];
  float4 yv = ((const float4*)yin)[base];
  float4 tv;
  tv.x = xv.x + yv.x; tv.y = xv.y + yv.y; tv.z = xv.z + yv.z; tv.w = xv.w + yv.w;
  float s = tv.x + tv.y + tv.z + tv.w;
  float s2 = tv.x * tv.x + tv.y * tv.y + tv.z * tv.z + tv.w * tv.w;
#pragma unroll
  for (int o = 1; o < 64; o <<= 1) {
    s += __shfl_xor(s, o, 64);
    s2 += __shfl_xor(s2, o, 64);
  }
  float mean = s * (1.0f / 256.0f);
  float var = s2 * (1.0f / 256.0f) - mean * mean;
  float rstd = rsqrtf(var + 1e-5f);
  float4 gv = ((const float4*)g)[lane];
  float4 bv = ((const float4*)bb)[lane];
  float4 o;
  o.x = gv.x * (tv.x - mean) * rstd + bv.x;
  o.y = gv.y * (tv.y - mean) * rstd + bv.y;
  o.z = gv.z * (tv.z - mean) * rstd + bv.z;
  o.w = gv.w * (tv.w - mean) * rstd + bv.w;
  ((float4*)xout)[base] = o;
  ushort4 ob;
  ob.x = f2bf(o.x); ob.y = f2bf(o.y); ob.z = f2bf(o.z); ob.w = f2bf(o.w);
  ((ushort4*)xbout)[base] = ob;
}

extern "C" void kernel_launch(void* const* d_in, const int* in_sizes, int n_in,
                              void* d_out, int out_size, void* d_ws, size_t ws_size,
                              hipStream_t stream) {
  (void)in_sizes; (void)n_in; (void)out_size; (void)ws_size;
  const float* src     = (const float*)d_in[0];
  const float* pos     = (const float*)d_in[1];
  const float* lev_emb = (const float*)d_in[2];
  const float* w_off   = (const float*)d_in[3];
  const float* b_off   = (const float*)d_in[4];
  const float* w_attn  = (const float*)d_in[5];
  const float* b_attn  = (const float*)d_in[6];
  const float* w_val   = (const float*)d_in[7];
  const float* b_val   = (const float*)d_in[8];
  const float* w_out   = (const float*)d_in[9];
  const float* b_out   = (const float*)d_in[10];
  const float* ln1_g   = (const float*)d_in[11];
  const float* ln1_b   = (const float*)d_in[12];
  const float* w_ff1   = (const float*)d_in[13];
  const float* b_ff1   = (const float*)d_in[14];
  const float* w_ff2   = (const float*)d_in[15];
  const float* b_ff2   = (const float*)d_in[16];
  const float* ln2_g   = (const float*)d_in[17];
  const float* ln2_b   = (const float*)d_in[18];

  char* ws = (char*)d_ws;
  float*          x     = (float*)(ws + 0);
  float*          y     = (float*)(ws + 22282240);   // also v (aliased in time)
  unsigned short* xb    = (unsigned short*)(ws + 44564480);
  unsigned short* qb    = (unsigned short*)(ws + 55705600);
  float*          offb  = (float*)(ws + 66846720);
  float*          attnb = (float*)(ws + 89128960);
  unsigned short* sampb = (unsigned short*)(ws + 100270080);
  unsigned short* h1    = (unsigned short*)(ws + 66846720); // alias off+attn+samp
  unsigned short* wT    = (unsigned short*)(ws + 111411200);

  wconv<<<17664, 256, 0, stream>>>(w_off, w_attn, w_val, w_out, w_ff1, w_ff2, wT);
  prep<<<5440, 256, 0, stream>>>(src, x, xb);

  for (int i = 0; i < 6; ++i) {
    const unsigned short* wl = wT + (size_t)i * 753664;
    qadd<<<5440, 256, 0, stream>>>(x, pos, lev_emb, qb);
    gemm_tn<false, false><<<dim3(170, 2), 256, 0, stream>>>(qb, wl + 0,      b_off + i * 256,  (void*)offb,  NTOK, 256, 256);
    gemm_tn<false, false><<<dim3(170, 1), 256, 0, stream>>>(qb, wl + 65536,  b_attn + i * 128, (void*)attnb, NTOK, 128, 256);
    gemm_tn<false, false><<<dim3(170, 2), 256, 0, stream>>>(xb, wl + 98304,  b_val + i * 256,  (void*)y,     NTOK, 256, 256);
    softmax16<<<680, 256, 0, stream>>>(attnb);
    ms_sample<<<NTOK, 256, 0, stream>>>(offb, attnb, y, sampb);
    gemm_tn<false, false><<<dim3(170, 2), 256, 0, stream>>>(sampb, wl + 163840, b_out + i * 256, (void*)y,   NTOK, 256, 256);
    ln_fused<<<5440, 256, 0, stream>>>(x, y, ln1_g + i * 256, ln1_b + i * 256, x, xb);
    gemm_tn<true,  true ><<<dim3(170, 8), 256, 0, stream>>>(xb, wl + 229376, b_ff1 + i * 1024, (void*)h1,    NTOK, 1024, 256);
    gemm_tn<false, false><<<dim3(170, 2), 256, 0, stream>>>(h1, wl + 491520, b_ff2 + i * 256,  (void*)y,     NTOK, 256, 1024);
    float* xo = (i == 5) ? (float*)d_out : x;
    ln_fused<<<5440, 256, 0, stream>>>(x, y, ln2_g + i * 256, ln2_b + i * 256, xo, xb);
  }
}

// Round 3
// 1288.257 us; speedup vs baseline: 1.0319x; 1.0319x over previous
//
#include <hip/hip_runtime.h>

#define LTOT 5440
#define NTOK 21760   // B*L = 4*5440

typedef float  f32x4  __attribute__((ext_vector_type(4)));
typedef short  short8 __attribute__((ext_vector_type(8)));

__device__ __forceinline__ unsigned short f2bf(float f) {
  unsigned int u = __float_as_uint(f);
  u += 0x7FFF + ((u >> 16) & 1);          // RNE
  return (unsigned short)(u >> 16);
}
__device__ __forceinline__ float bf2f(unsigned short u) {
  return __uint_as_float(((unsigned int)u) << 16);
}

// ---------------------------------------------------------------------------
// Weight convert+transpose: all six weight kinds, all 6 layers -> bf16 [N][K]
// per-layer (elements): off[256][256]@0, attn[128][256]@65536  (together =
// fused offattn [384][256]@0), val[256][256]@98304, out[256][256]@163840,
// ff1[1024][256]@229376, ff2[256][1024]@491520 ; layer stride 753664.
// ---------------------------------------------------------------------------
__global__ void wconv(const float* __restrict__ w_off, const float* __restrict__ w_attn,
                      const float* __restrict__ w_val, const float* __restrict__ w_out,
                      const float* __restrict__ w_ff1, const float* __restrict__ w_ff2,
                      unsigned short* __restrict__ dst) {
  int tid = blockIdx.x * 256 + threadIdx.x;
  const int PER = 753664;
  if (tid >= 6 * PER) return;
  int layer = tid / PER;
  int rem = tid - layer * PER;
  int base, K, N;
  const float* src;
  if (rem < 65536)       { base = 0;      K = 256;  N = 256;  src = w_off; }
  else if (rem < 98304)  { base = 65536;  K = 256;  N = 128;  src = w_attn; }
  else if (rem < 163840) { base = 98304;  K = 256;  N = 256;  src = w_val; }
  else if (rem < 229376) { base = 163840; K = 256;  N = 256;  src = w_out; }
  else if (rem < 491520) { base = 229376; K = 256;  N = 1024; src = w_ff1; }
  else                   { base = 491520; K = 1024; N = 256;  src = w_ff2; }
  int local = rem - base;
  int n = local / K, k = local - n * K;
  dst[tid] = f2bf(src[(size_t)layer * K * N + (size_t)k * N + n]);
}

// pack fused off+attn bias: fb[layer][384]
__global__ void bpack(const float* __restrict__ b_off, const float* __restrict__ b_attn,
                      float* __restrict__ fb) {
  int l = blockIdx.x, t = threadIdx.x;
  fb[l * 384 + t] = (t < 256) ? b_off[l * 256 + t] : b_attn[l * 128 + t - 256];
}

// x = src (f32 master) + bf16 shadow + qb = bf16(src + pos + lev_emb)
__global__ void prep(const float* __restrict__ src, const float* __restrict__ pos,
                     const float* __restrict__ lev_emb, float* __restrict__ x,
                     unsigned short* __restrict__ xb, unsigned short* __restrict__ qb) {
  int i = blockIdx.x * 256 + threadIdx.x;   // float4 index, NTOK*64 total
  int d4 = i & 63;
  int tok = (i >> 6) % LTOT;
  int lev = (tok < 64) ? 0 : (tok < 320) ? 1 : (tok < 1344) ? 2 : 3;
  float4 s = ((const float4*)src)[i];
  float4 pv = ((const float4*)pos)[i];
  float4 lv = ((const float4*)lev_emb)[lev * 64 + d4];
  ((float4*)x)[i] = s;
  ushort4 o;
  o.x = f2bf(s.x); o.y = f2bf(s.y); o.z = f2bf(s.z); o.w = f2bf(s.w);
  ((ushort4*)xb)[i] = o;
  ushort4 q;
  q.x = f2bf(s.x + pv.x + lv.x);
  q.y = f2bf(s.y + pv.y + lv.y);
  q.z = f2bf(s.z + pv.z + lv.z);
  q.w = f2bf(s.w + pv.w + lv.w);
  ((ushort4*)qb)[i] = q;
}

// ---------------------------------------------------------------------------
// bf16 MFMA GEMM, C = A[M][K] * Wt[N][K]^T + bias.  TN, 128x128 tile, BK=64,
// 4 waves (2x2), 16x16x32 fragments.
// ---------------------------------------------------------------------------
template<bool RELU, bool OBF16>
__global__ __launch_bounds__(256) void gemm_tn(
    const unsigned short* __restrict__ A, const unsigned short* __restrict__ Wt,
    const float* __restrict__ bias, void* __restrict__ Cout,
    int M, int N, int K) {
  __shared__ __align__(16) unsigned short a_lds[128 * 64];
  __shared__ __align__(16) unsigned short b_lds[128 * 64];
  int m0 = blockIdx.x * 128;
  int n0 = blockIdx.y * 128;
  int t = threadIdx.x;
  int w = t >> 6, l = t & 63;
  int wr = (w >> 1) * 64, wc = (w & 1) * 64;
  int lr = l & 15, lk = (l >> 4) * 8;

  f32x4 acc[4][4] = {};

  for (int k0 = 0; k0 < K; k0 += 64) {
#pragma unroll
    for (int i = 0; i < 4; ++i) {
      int c = i * 256 + t;
      int row = c >> 3, off8 = (c & 7) * 8;
      const unsigned short* gp = A + (size_t)(m0 + row) * K + k0 + off8;
      __builtin_amdgcn_global_load_lds(
          (const __attribute__((address_space(1))) void*)gp,
          (__attribute__((address_space(3))) void*)(a_lds + c * 8), 16, 0, 0);
    }
#pragma unroll
    for (int i = 0; i < 4; ++i) {
      int c = i * 256 + t;
      int row = c >> 3, off8 = (c & 7) * 8;
      const unsigned short* gp = Wt + (size_t)(n0 + row) * K + k0 + off8;
      __builtin_amdgcn_global_load_lds(
          (const __attribute__((address_space(1))) void*)gp,
          (__attribute__((address_space(3))) void*)(b_lds + c * 8), 16, 0, 0);
    }
    __syncthreads();
#pragma unroll
    for (int kk = 0; kk < 64; kk += 32) {
      short8 af[4], bfr[4];
#pragma unroll
      for (int m = 0; m < 4; ++m)
        af[m] = *(const short8*)(a_lds + (wr + m * 16 + lr) * 64 + kk + lk);
#pragma unroll
      for (int n = 0; n < 4; ++n)
        bfr[n] = *(const short8*)(b_lds + (wc + n * 16 + lr) * 64 + kk + lk);
#pragma unroll
      for (int m = 0; m < 4; ++m)
#pragma unroll
        for (int n = 0; n < 4; ++n)
          acc[m][n] = __builtin_amdgcn_mfma_f32_16x16x32_bf16(af[m], bfr[n], acc[m][n], 0, 0, 0);
    }
    __syncthreads();
  }

  int rb = (l >> 4) * 4;
#pragma unroll
  for (int n = 0; n < 4; ++n) {
    int col = n0 + wc + n * 16 + lr;
    float bv = bias[col];
#pragma unroll
    for (int m = 0; m < 4; ++m) {
#pragma unroll
      for (int r = 0; r < 4; ++r) {
        int row = m0 + wr + m * 16 + rb + r;
        float v = acc[m][n][r] + bv;
        if (RELU) v = fmaxf(v, 0.0f);
        if (OBF16) ((unsigned short*)Cout)[(size_t)row * N + col] = f2bf(v);
        else       ((float*)Cout)[(size_t)row * N + col] = v;
      }
    }
  }
}

// ---------------------------------------------------------------------------
// deformable sampling, fused softmax, bf16 v, XCD-swizzled blocks.
// one block per (b,l) token. phase1 (t<128 = h*16+lev*4+pt): softmax over the
// 16-group via shfl, corner indices + attn-premultiplied bilinear weights.
// phase2 (all 256 = h*32+dh): gather bf16 v, reduce 16 samples x 4 corners.
// ---------------------------------------------------------------------------
__global__ __launch_bounds__(256) void ms_sample(
    const float* __restrict__ offattn, const unsigned short* __restrict__ vb,
    unsigned short* __restrict__ samp) {
  __shared__ int   sIdx[128 * 4];
  __shared__ float sWt[128 * 4];
  int bid = blockIdx.x;
  int bl = (bid & 7) * (NTOK / 8) + (bid >> 3);   // XCD-contiguous tokens
  int t = threadIdx.x;
  int l = bl % LTOT;
  int bbase = (bl - l) * 256;              // b*L*256
  if (t < 128) {
    // fused softmax over (lev,pt) 16-group: masks 1,2,4,8 stay in-group
    float logit = offattn[(size_t)bl * 384 + 256 + t];
    float mx = logit;
#pragma unroll
    for (int o = 1; o < 16; o <<= 1) mx = fmaxf(mx, __shfl_xor(mx, o));
    float e = __expf(logit - mx);
    float ssum = e;
#pragma unroll
    for (int o = 1; o < 16; o <<= 1) ssum += __shfl_xor(ssum, o);
    float aw = e / ssum;

    int lev = (t >> 2) & 3;
    int lev_q = (l < 64) ? 0 : (l < 320) ? 1 : (l < 1344) ? 2 : 3;
    int start_q = (lev_q == 0) ? 0 : (lev_q == 1) ? 64 : (lev_q == 2) ? 320 : 1344;
    int shq = lev_q + 3;
    int r = l - start_q;
    int Wq = 1 << shq;
    int iy = r >> shq, ix = r & (Wq - 1);
    float invWq = 1.0f / (float)Wq;
    float refx = ((float)ix + 0.5f) * invWq;
    float refy = ((float)iy + 0.5f) * invWq;
    int iW = 8 << lev;
    float Wl = (float)iW;
    int start_l = (lev == 0) ? 0 : (lev == 1) ? 64 : (lev == 2) ? 320 : 1344;
    float ox = offattn[(size_t)bl * 384 + 2 * t];
    float oy = offattn[(size_t)bl * 384 + 2 * t + 1];
    // (ref + off/W)*W - 0.5 == ref*W + off - 0.5
    float gx = refx * Wl + ox - 0.5f;
    float gy = refy * Wl + oy - 0.5f;
    float flx = floorf(gx), fly = floorf(gy);
    int x0 = (int)flx, y0 = (int)fly;
    float fx = gx - flx, fy = gy - fly;
#pragma unroll
    for (int c = 0; c < 4; ++c) {
      int cx = x0 + (c & 1);
      int cy = y0 + (c >> 1);
      int inb = (cx >= 0) && (cx < iW) && (cy >= 0) && (cy < iW);
      int cxc = cx < 0 ? 0 : (cx > iW - 1 ? iW - 1 : cx);
      int cyc = cy < 0 ? 0 : (cy > iW - 1 ? iW - 1 : cy);
      float wx = (c & 1) ? fx : 1.0f - fx;
      float wy = (c & 2) ? fy : 1.0f - fy;
      sIdx[t * 4 + c] = (start_l + cyc * iW + cxc) * 256;
      sWt[t * 4 + c] = inb ? aw * wx * wy : 0.0f;
    }
  }
  __syncthreads();
  int h = t >> 5;
  int sbase = h * 64;                      // h's 16 samples * 4 corners
  float acc0 = 0.0f, acc1 = 0.0f;
#pragma unroll
  for (int s = 0; s < 16; ++s) {
    float w0 = sWt[sbase + s * 4 + 0]; int i0 = sIdx[sbase + s * 4 + 0];
    float w1 = sWt[sbase + s * 4 + 1]; int i1 = sIdx[sbase + s * 4 + 1];
    float w2 = sWt[sbase + s * 4 + 2]; int i2 = sIdx[sbase + s * 4 + 2];
    float w3 = sWt[sbase + s * 4 + 3]; int i3 = sIdx[sbase + s * 4 + 3];
    acc0 = fmaf(w0, bf2f(vb[bbase + i0 + t]), acc0);
    acc1 = fmaf(w1, bf2f(vb[bbase + i1 + t]), acc1);
    acc0 = fmaf(w2, bf2f(vb[bbase + i2 + t]), acc0);
    acc1 = fmaf(w3, bf2f(vb[bbase + i3 + t]), acc1);
  }
  samp[(size_t)bl * 256 + t] = f2bf(acc0 + acc1);
}

// x' = LN(x + y); writes f32 + bf16 shadow; QADD: also qb = bf16(x' + pos + lev_emb)
template<bool QADD>
__global__ __launch_bounds__(256) void ln_fused(
    const float* __restrict__ xin, const float* __restrict__ yin,
    const float* __restrict__ g, const float* __restrict__ bb,
    const float* __restrict__ pos, const float* __restrict__ lev_emb,
    float* __restrict__ xout, unsigned short* __restrict__ xbout,
    unsigned short* __restrict__ qbout) {
  int row = blockIdx.x * 4 + (threadIdx.x >> 6);
  int lane = threadIdx.x & 63;
  size_t base = (size_t)row * 64 + lane;   // float4 units
  float4 xv = ((const float4*)xin)[base];
  float4 yv = ((const float4*)yin)[base];
  float4 tv;
  tv.x = xv.x + yv.x; tv.y = xv.y + yv.y; tv.z = xv.z + yv.z; tv.w = xv.w + yv.w;
  float s = tv.x + tv.y + tv.z + tv.w;
  float s2 = tv.x * tv.x + tv.y * tv.y + tv.z * tv.z + tv.w * tv.w;
#pragma unroll
  for (int o = 1; o < 64; o <<= 1) {
    s += __shfl_xor(s, o, 64);
    s2 += __shfl_xor(s2, o, 64);
  }
  float mean = s * (1.0f / 256.0f);
  float var = s2 * (1.0f / 256.0f) - mean * mean;
  float rstd = rsqrtf(var + 1e-5f);
  float4 gv = ((const float4*)g)[lane];
  float4 bv = ((const float4*)bb)[lane];
  float4 o;
  o.x = gv.x * (tv.x - mean) * rstd + bv.x;
  o.y = gv.y * (tv.y - mean) * rstd + bv.y;
  o.z = gv.z * (tv.z - mean) * rstd + bv.z;
  o.w = gv.w * (tv.w - mean) * rstd + bv.w;
  ((float4*)xout)[base] = o;
  ushort4 ob;
  ob.x = f2bf(o.x); ob.y = f2bf(o.y); ob.z = f2bf(o.z); ob.w = f2bf(o.w);
  ((ushort4*)xbout)[base] = ob;
  if (QADD) {
    int tok = row % LTOT;
    int lev = (tok < 64) ? 0 : (tok < 320) ? 1 : (tok < 1344) ? 2 : 3;
    float4 pv = ((const float4*)pos)[base];
    float4 lv = ((const float4*)lev_emb)[lev * 64 + lane];
    ushort4 q;
    q.x = f2bf(o.x + pv.x + lv.x);
    q.y = f2bf(o.y + pv.y + lv.y);
    q.z = f2bf(o.z + pv.z + lv.z);
    q.w = f2bf(o.w + pv.w + lv.w);
    ((ushort4*)qbout)[base] = q;
  }
}

extern "C" void kernel_launch(void* const* d_in, const int* in_sizes, int n_in,
                              void* d_out, int out_size, void* d_ws, size_t ws_size,
                              hipStream_t stream) {
  (void)in_sizes; (void)n_in; (void)out_size; (void)ws_size;
  const float* src     = (const float*)d_in[0];
  const float* pos     = (const float*)d_in[1];
  const float* lev_emb = (const float*)d_in[2];
  const float* w_off   = (const float*)d_in[3];
  const float* b_off   = (const float*)d_in[4];
  const float* w_attn  = (const float*)d_in[5];
  const float* b_attn  = (const float*)d_in[6];
  const float* w_val   = (const float*)d_in[7];
  const float* b_val   = (const float*)d_in[8];
  const float* w_out   = (const float*)d_in[9];
  const float* b_out   = (const float*)d_in[10];
  const float* ln1_g   = (const float*)d_in[11];
  const float* ln1_b   = (const float*)d_in[12];
  const float* w_ff1   = (const float*)d_in[13];
  const float* b_ff1   = (const float*)d_in[14];
  const float* w_ff2   = (const float*)d_in[15];
  const float* b_ff2   = (const float*)d_in[16];
  const float* ln2_g   = (const float*)d_in[17];
  const float* ln2_b   = (const float*)d_in[18];

  char* ws = (char*)d_ws;
  float*          x     = (float*)(ws + 0);
  float*          y     = (float*)(ws + 22282240);
  unsigned short* xb    = (unsigned short*)(ws + 44564480);
  unsigned short* qb    = (unsigned short*)(ws + 55705600);  // aliased w/ sampb
  unsigned short* sampb = (unsigned short*)(ws + 55705600);  // (disjoint lifetimes)
  float*          offat = (float*)(ws + 66846720);           // [NTOK][384]
  unsigned short* vb    = (unsigned short*)(ws + 100270080);
  unsigned short* h1    = (unsigned short*)(ws + 66846720);  // alias offat+vb
  unsigned short* wT    = (unsigned short*)(ws + 111411200);
  float*          fb    = (float*)(ws + 120455168);          // fused bias [6][384]

  wconv<<<17664, 256, 0, stream>>>(w_off, w_attn, w_val, w_out, w_ff1, w_ff2, wT);
  bpack<<<6, 384, 0, stream>>>(b_off, b_attn, fb);
  prep<<<5440, 256, 0, stream>>>(src, pos, lev_emb, x, xb, qb);

  for (int i = 0; i < 6; ++i) {
    const unsigned short* wl = wT + (size_t)i * 753664;
    gemm_tn<false, false><<<dim3(170, 3), 256, 0, stream>>>(qb, wl + 0,      fb + i * 384,     (void*)offat, NTOK, 384, 256);
    gemm_tn<false, true ><<<dim3(170, 2), 256, 0, stream>>>(xb, wl + 98304,  b_val + i * 256,  (void*)vb,    NTOK, 256, 256);
    ms_sample<<<NTOK, 256, 0, stream>>>(offat, vb, sampb);
    gemm_tn<false, false><<<dim3(170, 2), 256, 0, stream>>>(sampb, wl + 163840, b_out + i * 256, (void*)y,   NTOK, 256, 256);
    ln_fused<false><<<5440, 256, 0, stream>>>(x, y, ln1_g + i * 256, ln1_b + i * 256, pos, lev_emb, x, xb, qb);
    gemm_tn<true,  true ><<<dim3(170, 8), 256, 0, stream>>>(xb, wl + 229376, b_ff1 + i * 1024, (void*)h1,    NTOK, 1024, 256);
    gemm_tn<false, false><<<dim3(170, 2), 256, 0, stream>>>(h1, wl + 491520, b_ff2 + i * 256,  (void*)y,     NTOK, 256, 1024);
    float* xo = (i == 5) ? (float*)d_out : x;
    if (i < 5)
      ln_fused<true ><<<5440, 256, 0, stream>>>(x, y, ln2_g + i * 256, ln2_b + i * 256, pos, lev_emb, xo, xb, qb);
    else
      ln_fused<false><<<5440, 256, 0, stream>>>(x, y, ln2_g + i * 256, ln2_b + i * 256, pos, lev_emb, xo, xb, qb);
  }
}

// Round 4
// 1213.719 us; speedup vs baseline: 1.0952x; 1.0614x over previous
//
#include <hip/hip_runtime.h>

#define LTOT 5440
#define NTOK 21760   // B*L = 4*5440

typedef float  f32x4  __attribute__((ext_vector_type(4)));
typedef short  short8 __attribute__((ext_vector_type(8)));

__device__ __forceinline__ unsigned short f2bf(float f) {
  unsigned int u = __float_as_uint(f);
  u += 0x7FFF + ((u >> 16) & 1);          // RNE
  return (unsigned short)(u >> 16);
}
__device__ __forceinline__ float bf2f(unsigned short u) {
  return __uint_as_float(((unsigned int)u) << 16);
}

// ---------------------------------------------------------------------------
// Weight convert+transpose: all six weight kinds, all 6 layers -> bf16 [N][K]
// per-layer (elements): off[256][256]@0, attn[128][256]@65536  (together =
// fused offattn [384][256]@0), val[256][256]@98304, out[256][256]@163840,
// ff1[1024][256]@229376, ff2[256][1024]@491520 ; layer stride 753664.
// ---------------------------------------------------------------------------
__global__ void wconv(const float* __restrict__ w_off, const float* __restrict__ w_attn,
                      const float* __restrict__ w_val, const float* __restrict__ w_out,
                      const float* __restrict__ w_ff1, const float* __restrict__ w_ff2,
                      unsigned short* __restrict__ dst) {
  int tid = blockIdx.x * 256 + threadIdx.x;
  const int PER = 753664;
  if (tid >= 6 * PER) return;
  int layer = tid / PER;
  int rem = tid - layer * PER;
  int base, K, N;
  const float* src;
  if (rem < 65536)       { base = 0;      K = 256;  N = 256;  src = w_off; }
  else if (rem < 98304)  { base = 65536;  K = 256;  N = 128;  src = w_attn; }
  else if (rem < 163840) { base = 98304;  K = 256;  N = 256;  src = w_val; }
  else if (rem < 229376) { base = 163840; K = 256;  N = 256;  src = w_out; }
  else if (rem < 491520) { base = 229376; K = 256;  N = 1024; src = w_ff1; }
  else                   { base = 491520; K = 1024; N = 256;  src = w_ff2; }
  int local = rem - base;
  int n = local / K, k = local - n * K;
  dst[tid] = f2bf(src[(size_t)layer * K * N + (size_t)k * N + n]);
}

// pack fused off+attn bias: fb[layer][384]
__global__ void bpack(const float* __restrict__ b_off, const float* __restrict__ b_attn,
                      float* __restrict__ fb) {
  int l = blockIdx.x, t = threadIdx.x;
  fb[l * 384 + t] = (t < 256) ? b_off[l * 256 + t] : b_attn[l * 128 + t - 256];
}

// x = src (f32 master) + bf16 shadow + qb = bf16(src + pos + lev_emb)
__global__ void prep(const float* __restrict__ src, const float* __restrict__ pos,
                     const float* __restrict__ lev_emb, float* __restrict__ x,
                     unsigned short* __restrict__ xb, unsigned short* __restrict__ qb) {
  int i = blockIdx.x * 256 + threadIdx.x;   // float4 index, NTOK*64 total
  int d4 = i & 63;
  int tok = (i >> 6) % LTOT;
  int lev = (tok < 64) ? 0 : (tok < 320) ? 1 : (tok < 1344) ? 2 : 3;
  float4 s = ((const float4*)src)[i];
  float4 pv = ((const float4*)pos)[i];
  float4 lv = ((const float4*)lev_emb)[lev * 64 + d4];
  ((float4*)x)[i] = s;
  ushort4 o;
  o.x = f2bf(s.x); o.y = f2bf(s.y); o.z = f2bf(s.z); o.w = f2bf(s.w);
  ((ushort4*)xb)[i] = o;
  ushort4 q;
  q.x = f2bf(s.x + pv.x + lv.x);
  q.y = f2bf(s.y + pv.y + lv.y);
  q.z = f2bf(s.z + pv.z + lv.z);
  q.w = f2bf(s.w + pv.w + lv.w);
  ((ushort4*)qb)[i] = q;
}

// ---------------------------------------------------------------------------
// bf16 MFMA GEMM, C = A[M][K] * Wt[N][K]^T + bias.  TN, 128x128 tile, BK=64,
// 4 waves (2x2), 16x16x32 fragments.
// ---------------------------------------------------------------------------
template<bool RELU, bool OBF16>
__global__ __launch_bounds__(256) void gemm_tn(
    const unsigned short* __restrict__ A, const unsigned short* __restrict__ Wt,
    const float* __restrict__ bias, void* __restrict__ Cout,
    int M, int N, int K) {
  __shared__ __align__(16) unsigned short a_lds[128 * 64];
  __shared__ __align__(16) unsigned short b_lds[128 * 64];
  int m0 = blockIdx.x * 128;
  int n0 = blockIdx.y * 128;
  int t = threadIdx.x;
  int w = t >> 6, l = t & 63;
  int wr = (w >> 1) * 64, wc = (w & 1) * 64;
  int lr = l & 15, lk = (l >> 4) * 8;

  f32x4 acc[4][4] = {};

  for (int k0 = 0; k0 < K; k0 += 64) {
#pragma unroll
    for (int i = 0; i < 4; ++i) {
      int c = i * 256 + t;
      int row = c >> 3, off8 = (c & 7) * 8;
      const unsigned short* gp = A + (size_t)(m0 + row) * K + k0 + off8;
      __builtin_amdgcn_global_load_lds(
          (const __attribute__((address_space(1))) void*)gp,
          (__attribute__((address_space(3))) void*)(a_lds + c * 8), 16, 0, 0);
    }
#pragma unroll
    for (int i = 0; i < 4; ++i) {
      int c = i * 256 + t;
      int row = c >> 3, off8 = (c & 7) * 8;
      const unsigned short* gp = Wt + (size_t)(n0 + row) * K + k0 + off8;
      __builtin_amdgcn_global_load_lds(
          (const __attribute__((address_space(1))) void*)gp,
          (__attribute__((address_space(3))) void*)(b_lds + c * 8), 16, 0, 0);
    }
    __syncthreads();
#pragma unroll
    for (int kk = 0; kk < 64; kk += 32) {
      short8 af[4], bfr[4];
#pragma unroll
      for (int m = 0; m < 4; ++m)
        af[m] = *(const short8*)(a_lds + (wr + m * 16 + lr) * 64 + kk + lk);
#pragma unroll
      for (int n = 0; n < 4; ++n)
        bfr[n] = *(const short8*)(b_lds + (wc + n * 16 + lr) * 64 + kk + lk);
#pragma unroll
      for (int m = 0; m < 4; ++m)
#pragma unroll
        for (int n = 0; n < 4; ++n)
          acc[m][n] = __builtin_amdgcn_mfma_f32_16x16x32_bf16(af[m], bfr[n], acc[m][n], 0, 0, 0);
    }
    __syncthreads();
  }

  int rb = (l >> 4) * 4;
#pragma unroll
  for (int n = 0; n < 4; ++n) {
    int col = n0 + wc + n * 16 + lr;
    float bv = bias[col];
#pragma unroll
    for (int m = 0; m < 4; ++m) {
#pragma unroll
      for (int r = 0; r < 4; ++r) {
        int row = m0 + wr + m * 16 + rb + r;
        float v = acc[m][n][r] + bv;
        if (RELU) v = fmaxf(v, 0.0f);
        if (OBF16) ((unsigned short*)Cout)[(size_t)row * N + col] = f2bf(v);
        else       ((float*)Cout)[(size_t)row * N + col] = v;
      }
    }
  }
}

// ---------------------------------------------------------------------------
// deformable sampling v2: fused softmax, bf16 v, XCD-swizzled blocks,
// 2-channels-per-thread gather (u32 loads), sample-halves split + shfl merge.
// phase1 (t<128 = h*16+lev*4+pt): softmax 16-group via shfl, corner idx +
//   attn-premultiplied bilinear weights into LDS.
// phase2: t = h*32+j ; p=j&15 -> channels (2p,2p+1); half=j>>4 -> samples
//   half*8..half*8+7. 32 corner-loads of u32 each; LDS k-walk rotated per
//   (h,half) so the 4 uniform addresses/wave hit distinct banks.
// ---------------------------------------------------------------------------
__global__ __launch_bounds__(256) void ms_sample(
    const float* __restrict__ offattn, const unsigned short* __restrict__ vb,
    unsigned short* __restrict__ samp) {
  __shared__ int   sIdx[128 * 4];
  __shared__ float sWt[128 * 4];
  int bid = blockIdx.x;
  int bl = (bid & 7) * (NTOK / 8) + (bid >> 3);   // XCD-contiguous tokens
  int t = threadIdx.x;
  int l = bl % LTOT;
  int bbase = (bl - l) * 256;              // b*L*256
  if (t < 128) {
    // fused softmax over (lev,pt) 16-group: masks 1,2,4,8 stay in-group
    float logit = offattn[(size_t)bl * 384 + 256 + t];
    float mx = logit;
#pragma unroll
    for (int o = 1; o < 16; o <<= 1) mx = fmaxf(mx, __shfl_xor(mx, o));
    float e = __expf(logit - mx);
    float ssum = e;
#pragma unroll
    for (int o = 1; o < 16; o <<= 1) ssum += __shfl_xor(ssum, o);
    float aw = e / ssum;

    int lev = (t >> 2) & 3;
    int lev_q = (l < 64) ? 0 : (l < 320) ? 1 : (l < 1344) ? 2 : 3;
    int start_q = (lev_q == 0) ? 0 : (lev_q == 1) ? 64 : (lev_q == 2) ? 320 : 1344;
    int shq = lev_q + 3;
    int r = l - start_q;
    int Wq = 1 << shq;
    int iy = r >> shq, ix = r & (Wq - 1);
    float invWq = 1.0f / (float)Wq;
    float refx = ((float)ix + 0.5f) * invWq;
    float refy = ((float)iy + 0.5f) * invWq;
    int iW = 8 << lev;
    float Wl = (float)iW;
    int start_l = (lev == 0) ? 0 : (lev == 1) ? 64 : (lev == 2) ? 320 : 1344;
    float ox = offattn[(size_t)bl * 384 + 2 * t];
    float oy = offattn[(size_t)bl * 384 + 2 * t + 1];
    // (ref + off/W)*W - 0.5 == ref*W + off - 0.5
    float gx = refx * Wl + ox - 0.5f;
    float gy = refy * Wl + oy - 0.5f;
    float flx = floorf(gx), fly = floorf(gy);
    int x0 = (int)flx, y0 = (int)fly;
    float fx = gx - flx, fy = gy - fly;
#pragma unroll
    for (int c = 0; c < 4; ++c) {
      int cx = x0 + (c & 1);
      int cy = y0 + (c >> 1);
      int inb = (cx >= 0) && (cx < iW) && (cy >= 0) && (cy < iW);
      int cxc = cx < 0 ? 0 : (cx > iW - 1 ? iW - 1 : cx);
      int cyc = cy < 0 ? 0 : (cy > iW - 1 ? iW - 1 : cy);
      float wx = (c & 1) ? fx : 1.0f - fx;
      float wy = (c & 2) ? fy : 1.0f - fy;
      sIdx[t * 4 + c] = (start_l + cyc * iW + cxc) * 256;
      sWt[t * 4 + c] = inb ? aw * wx * wy : 0.0f;
    }
  }
  __syncthreads();
  int h = t >> 5, j = t & 31;
  int p = j & 15;                  // channel pair -> channels 2p, 2p+1
  int half = j >> 4;               // sample half: 0 -> k 0..31, 1 -> k 32..63
  int ch = h * 32 + p * 2;         // element offset of low channel in a v row
  int sb = h * 64 + half * 32;     // base into sIdx/sWt (32 corner-slots)
  int rot = h * 8 + half * 4;      // bank-decollision rotation
  const unsigned short* vp = vb + bbase + ch;
  float a0e = 0.0f, a1e = 0.0f, a0o = 0.0f, a1o = 0.0f;
#pragma unroll
  for (int k = 0; k < 32; k += 2) {
    int k0 = (k + rot) & 31;
    int k1 = (k + 1 + rot) & 31;
    float w0 = sWt[sb + k0]; int i0 = sIdx[sb + k0];
    float w1 = sWt[sb + k1]; int i1 = sIdx[sb + k1];
    unsigned int u0 = *(const unsigned int*)(vp + i0);
    unsigned int u1 = *(const unsigned int*)(vp + i1);
    a0e = fmaf(w0, __uint_as_float(u0 << 16), a0e);
    a1e = fmaf(w0, __uint_as_float(u0 & 0xffff0000u), a1e);
    a0o = fmaf(w1, __uint_as_float(u1 << 16), a0o);
    a1o = fmaf(w1, __uint_as_float(u1 & 0xffff0000u), a1o);
  }
  float a0 = a0e + a0o, a1 = a1e + a1o;
  a0 += __shfl_xor(a0, 16);
  a1 += __shfl_xor(a1, 16);
  if (half == 0) {
    unsigned int pk = (unsigned int)f2bf(a0) | ((unsigned int)f2bf(a1) << 16);
    *(unsigned int*)(samp + (size_t)bl * 256 + ch) = pk;
  }
}

// x' = LN(x + y); writes f32 + bf16 shadow; QADD: also qb = bf16(x' + pos + lev_emb)
template<bool QADD>
__global__ __launch_bounds__(256) void ln_fused(
    const float* __restrict__ xin, const float* __restrict__ yin,
    const float* __restrict__ g, const float* __restrict__ bb,
    const float* __restrict__ pos, const float* __restrict__ lev_emb,
    float* __restrict__ xout, unsigned short* __restrict__ xbout,
    unsigned short* __restrict__ qbout) {
  int row = blockIdx.x * 4 + (threadIdx.x >> 6);
  int lane = threadIdx.x & 63;
  size_t base = (size_t)row * 64 + lane;   // float4 units
  float4 xv = ((const float4*)xin)[base];
  float4 yv = ((const float4*)yin)[base];
  float4 tv;
  tv.x = xv.x + yv.x; tv.y = xv.y + yv.y; tv.z = xv.z + yv.z; tv.w = xv.w + yv.w;
  float s = tv.x + tv.y + tv.z + tv.w;
  float s2 = tv.x * tv.x + tv.y * tv.y + tv.z * tv.z + tv.w * tv.w;
#pragma unroll
  for (int o = 1; o < 64; o <<= 1) {
    s += __shfl_xor(s, o, 64);
    s2 += __shfl_xor(s2, o, 64);
  }
  float mean = s * (1.0f / 256.0f);
  float var = s2 * (1.0f / 256.0f) - mean * mean;
  float rstd = rsqrtf(var + 1e-5f);
  float4 gv = ((const float4*)g)[lane];
  float4 bv = ((const float4*)bb)[lane];
  float4 o;
  o.x = gv.x * (tv.x - mean) * rstd + bv.x;
  o.y = gv.y * (tv.y - mean) * rstd + bv.y;
  o.z = gv.z * (tv.z - mean) * rstd + bv.z;
  o.w = gv.w * (tv.w - mean) * rstd + bv.w;
  ((float4*)xout)[base] = o;
  ushort4 ob;
  ob.x = f2bf(o.x); ob.y = f2bf(o.y); ob.z = f2bf(o.z); ob.w = f2bf(o.w);
  ((ushort4*)xbout)[base] = ob;
  if (QADD) {
    int tok = row % LTOT;
    int lev = (tok < 64) ? 0 : (tok < 320) ? 1 : (tok < 1344) ? 2 : 3;
    float4 pv = ((const float4*)pos)[base];
    float4 lv = ((const float4*)lev_emb)[lev * 64 + lane];
    ushort4 q;
    q.x = f2bf(o.x + pv.x + lv.x);
    q.y = f2bf(o.y + pv.y + lv.y);
    q.z = f2bf(o.z + pv.z + lv.z);
    q.w = f2bf(o.w + pv.w + lv.w);
    ((ushort4*)qbout)[base] = q;
  }
}

extern "C" void kernel_launch(void* const* d_in, const int* in_sizes, int n_in,
                              void* d_out, int out_size, void* d_ws, size_t ws_size,
                              hipStream_t stream) {
  (void)in_sizes; (void)n_in; (void)out_size; (void)ws_size;
  const float* src     = (const float*)d_in[0];
  const float* pos     = (const float*)d_in[1];
  const float* lev_emb = (const float*)d_in[2];
  const float* w_off   = (const float*)d_in[3];
  const float* b_off   = (const float*)d_in[4];
  const float* w_attn  = (const float*)d_in[5];
  const float* b_attn  = (const float*)d_in[6];
  const float* w_val   = (const float*)d_in[7];
  const float* b_val   = (const float*)d_in[8];
  const float* w_out   = (const float*)d_in[9];
  const float* b_out   = (const float*)d_in[10];
  const float* ln1_g   = (const float*)d_in[11];
  const float* ln1_b   = (const float*)d_in[12];
  const float* w_ff1   = (const float*)d_in[13];
  const float* b_ff1   = (const float*)d_in[14];
  const float* w_ff2   = (const float*)d_in[15];
  const float* b_ff2   = (const float*)d_in[16];
  const float* ln2_g   = (const float*)d_in[17];
  const float* ln2_b   = (const float*)d_in[18];

  char* ws = (char*)d_ws;
  float*          x     = (float*)(ws + 0);
  float*          y     = (float*)(ws + 22282240);
  unsigned short* xb    = (unsigned short*)(ws + 44564480);
  unsigned short* qb    = (unsigned short*)(ws + 55705600);  // aliased w/ sampb
  unsigned short* sampb = (unsigned short*)(ws + 55705600);  // (disjoint lifetimes)
  float*          offat = (float*)(ws + 66846720);           // [NTOK][384]
  unsigned short* vb    = (unsigned short*)(ws + 100270080);
  unsigned short* h1    = (unsigned short*)(ws + 66846720);  // alias offat+vb
  unsigned short* wT    = (unsigned short*)(ws + 111411200);
  float*          fb    = (float*)(ws + 120455168);          // fused bias [6][384]

  wconv<<<17664, 256, 0, stream>>>(w_off, w_attn, w_val, w_out, w_ff1, w_ff2, wT);
  bpack<<<6, 384, 0, stream>>>(b_off, b_attn, fb);
  prep<<<5440, 256, 0, stream>>>(src, pos, lev_emb, x, xb, qb);

  for (int i = 0; i < 6; ++i) {
    const unsigned short* wl = wT + (size_t)i * 753664;
    gemm_tn<false, false><<<dim3(170, 3), 256, 0, stream>>>(qb, wl + 0,      fb + i * 384,     (void*)offat, NTOK, 384, 256);
    gemm_tn<false, true ><<<dim3(170, 2), 256, 0, stream>>>(xb, wl + 98304,  b_val + i * 256,  (void*)vb,    NTOK, 256, 256);
    ms_sample<<<NTOK, 256, 0, stream>>>(offat, vb, sampb);
    gemm_tn<false, false><<<dim3(170, 2), 256, 0, stream>>>(sampb, wl + 163840, b_out + i * 256, (void*)y,   NTOK, 256, 256);
    ln_fused<false><<<5440, 256, 0, stream>>>(x, y, ln1_g + i * 256, ln1_b + i * 256, pos, lev_emb, x, xb, qb);
    gemm_tn<true,  true ><<<dim3(170, 8), 256, 0, stream>>>(xb, wl + 229376, b_ff1 + i * 1024, (void*)h1,    NTOK, 1024, 256);
    gemm_tn<false, false><<<dim3(170, 2), 256, 0, stream>>>(h1, wl + 491520, b_ff2 + i * 256,  (void*)y,     NTOK, 256, 1024);
    float* xo = (i == 5) ? (float*)d_out : x;
    if (i < 5)
      ln_fused<true ><<<5440, 256, 0, stream>>>(x, y, ln2_g + i * 256, ln2_b + i * 256, pos, lev_emb, xo, xb, qb);
    else
      ln_fused<false><<<5440, 256, 0, stream>>>(x, y, ln2_g + i * 256, ln2_b + i * 256, pos, lev_emb, xo, xb, qb);
  }
}

// Round 5
// 1204.831 us; speedup vs baseline: 1.1033x; 1.0074x over previous
//
#include <hip/hip_runtime.h>

#define LTOT 5440
#define NTOK 21760   // B*L = 4*5440

typedef float  f32x4  __attribute__((ext_vector_type(4)));
typedef float  f32x2  __attribute__((ext_vector_type(2)));
typedef short  short8 __attribute__((ext_vector_type(8)));

__device__ __forceinline__ unsigned short f2bf(float f) {
  unsigned int u = __float_as_uint(f);
  u += 0x7FFF + ((u >> 16) & 1);          // RNE
  return (unsigned short)(u >> 16);
}
__device__ __forceinline__ float bf2f(unsigned short u) {
  return __uint_as_float(((unsigned int)u) << 16);
}

// ---------------------------------------------------------------------------
// Weight convert+transpose: all six weight kinds, all 6 layers -> bf16 [N][K]
// per-layer (elements): off[256][256]@0, attn[128][256]@65536  (together =
// fused offattn [384][256]@0), val[256][256]@98304, out[256][256]@163840,
// ff1[1024][256]@229376, ff2[256][1024]@491520 ; layer stride 753664.
// ---------------------------------------------------------------------------
__global__ void wconv(const float* __restrict__ w_off, const float* __restrict__ w_attn,
                      const float* __restrict__ w_val, const float* __restrict__ w_out,
                      const float* __restrict__ w_ff1, const float* __restrict__ w_ff2,
                      unsigned short* __restrict__ dst) {
  int tid = blockIdx.x * 256 + threadIdx.x;
  const int PER = 753664;
  if (tid >= 6 * PER) return;
  int layer = tid / PER;
  int rem = tid - layer * PER;
  int base, K, N;
  const float* src;
  if (rem < 65536)       { base = 0;      K = 256;  N = 256;  src = w_off; }
  else if (rem < 98304)  { base = 65536;  K = 256;  N = 128;  src = w_attn; }
  else if (rem < 163840) { base = 98304;  K = 256;  N = 256;  src = w_val; }
  else if (rem < 229376) { base = 163840; K = 256;  N = 256;  src = w_out; }
  else if (rem < 491520) { base = 229376; K = 256;  N = 1024; src = w_ff1; }
  else                   { base = 491520; K = 1024; N = 256;  src = w_ff2; }
  int local = rem - base;
  int n = local / K, k = local - n * K;
  dst[tid] = f2bf(src[(size_t)layer * K * N + (size_t)k * N + n]);
}

// pack fused off+attn bias: fb[layer][384]
__global__ void bpack(const float* __restrict__ b_off, const float* __restrict__ b_attn,
                      float* __restrict__ fb) {
  int l = blockIdx.x, t = threadIdx.x;
  fb[l * 384 + t] = (t < 256) ? b_off[l * 256 + t] : b_attn[l * 128 + t - 256];
}

// x = src (f32 master) + bf16 shadow + qb = bf16(src + pos + lev_emb)
__global__ void prep(const float* __restrict__ src, const float* __restrict__ pos,
                     const float* __restrict__ lev_emb, float* __restrict__ x,
                     unsigned short* __restrict__ xb, unsigned short* __restrict__ qb) {
  int i = blockIdx.x * 256 + threadIdx.x;   // float4 index, NTOK*64 total
  int d4 = i & 63;
  int tok = (i >> 6) % LTOT;
  int lev = (tok < 64) ? 0 : (tok < 320) ? 1 : (tok < 1344) ? 2 : 3;
  float4 s = ((const float4*)src)[i];
  float4 pv = ((const float4*)pos)[i];
  float4 lv = ((const float4*)lev_emb)[lev * 64 + d4];
  ((float4*)x)[i] = s;
  ushort4 o;
  o.x = f2bf(s.x); o.y = f2bf(s.y); o.z = f2bf(s.z); o.w = f2bf(s.w);
  ((ushort4*)xb)[i] = o;
  ushort4 q;
  q.x = f2bf(s.x + pv.x + lv.x);
  q.y = f2bf(s.y + pv.y + lv.y);
  q.z = f2bf(s.z + pv.z + lv.z);
  q.w = f2bf(s.w + pv.w + lv.w);
  ((ushort4*)qb)[i] = q;
}

// ---------------------------------------------------------------------------
// bf16 MFMA GEMM, C = A[M][K] * Wt[N][K]^T + bias.  TN, 128x128 tile, BK=64,
// 4 waves (2x2), 16x16x32 fragments.
// ---------------------------------------------------------------------------
template<bool RELU, bool OBF16>
__global__ __launch_bounds__(256) void gemm_tn(
    const unsigned short* __restrict__ A, const unsigned short* __restrict__ Wt,
    const float* __restrict__ bias, void* __restrict__ Cout,
    int M, int N, int K) {
  __shared__ __align__(16) unsigned short a_lds[128 * 64];
  __shared__ __align__(16) unsigned short b_lds[128 * 64];
  int m0 = blockIdx.x * 128;
  int n0 = blockIdx.y * 128;
  int t = threadIdx.x;
  int w = t >> 6, l = t & 63;
  int wr = (w >> 1) * 64, wc = (w & 1) * 64;
  int lr = l & 15, lk = (l >> 4) * 8;

  f32x4 acc[4][4] = {};

  for (int k0 = 0; k0 < K; k0 += 64) {
#pragma unroll
    for (int i = 0; i < 4; ++i) {
      int c = i * 256 + t;
      int row = c >> 3, off8 = (c & 7) * 8;
      const unsigned short* gp = A + (size_t)(m0 + row) * K + k0 + off8;
      __builtin_amdgcn_global_load_lds(
          (const __attribute__((address_space(1))) void*)gp,
          (__attribute__((address_space(3))) void*)(a_lds + c * 8), 16, 0, 0);
    }
#pragma unroll
    for (int i = 0; i < 4; ++i) {
      int c = i * 256 + t;
      int row = c >> 3, off8 = (c & 7) * 8;
      const unsigned short* gp = Wt + (size_t)(n0 + row) * K + k0 + off8;
      __builtin_amdgcn_global_load_lds(
          (const __attribute__((address_space(1))) void*)gp,
          (__attribute__((address_space(3))) void*)(b_lds + c * 8), 16, 0, 0);
    }
    __syncthreads();
#pragma unroll
    for (int kk = 0; kk < 64; kk += 32) {
      short8 af[4], bfr[4];
#pragma unroll
      for (int m = 0; m < 4; ++m)
        af[m] = *(const short8*)(a_lds + (wr + m * 16 + lr) * 64 + kk + lk);
#pragma unroll
      for (int n = 0; n < 4; ++n)
        bfr[n] = *(const short8*)(b_lds + (wc + n * 16 + lr) * 64 + kk + lk);
#pragma unroll
      for (int m = 0; m < 4; ++m)
#pragma unroll
        for (int n = 0; n < 4; ++n)
          acc[m][n] = __builtin_amdgcn_mfma_f32_16x16x32_bf16(af[m], bfr[n], acc[m][n], 0, 0, 0);
    }
    __syncthreads();
  }

  int rb = (l >> 4) * 4;
#pragma unroll
  for (int n = 0; n < 4; ++n) {
    int col = n0 + wc + n * 16 + lr;
    float bv = bias[col];
#pragma unroll
    for (int m = 0; m < 4; ++m) {
#pragma unroll
      for (int r = 0; r < 4; ++r) {
        int row = m0 + wr + m * 16 + rb + r;
        float v = acc[m][n][r] + bv;
        if (RELU) v = fmaxf(v, 0.0f);
        if (OBF16) ((unsigned short*)Cout)[(size_t)row * N + col] = f2bf(v);
        else       ((float*)Cout)[(size_t)row * N + col] = v;
      }
    }
  }
}

// ---------------------------------------------------------------------------
// deformable sampling v3: fused softmax, bf16 v, XCD-swizzled blocks.
// phase1 (t<128 = h*16+lev*4+pt): softmax 16-group via shfl; write (w, byte-
//   idx) interleaved as uint2 into LDS.
// phase2: t = h*32 + j ; q=j>>3 owns 16 corner-slots, p=j&7 -> 4 channels
//   (h*32+p*4..+3). ds_read_b128 = 2 slots; pair-rotation rotp=((h&1)<<2)|q
//   puts the wave's 8 broadcast groups on disjoint 4-bank sets. Gathers are
//   dwordx2 at uniform-base + 32-bit offset; packed f32x2 fma accumulation;
//   quarter-merge via shfl_xor(8,16); q==0 lanes store packed 4xbf16.
// ---------------------------------------------------------------------------
__global__ __launch_bounds__(256) void ms_sample(
    const float* __restrict__ offattn, const unsigned short* __restrict__ vb,
    unsigned short* __restrict__ samp) {
  __shared__ __align__(16) uint2 sWI[512];   // [h][64 slots] (w bits, byte idx)
  int bid = blockIdx.x;
  int bl = (bid & 7) * (NTOK / 8) + (bid >> 3);   // XCD-contiguous tokens
  int t = threadIdx.x;
  int l = bl % LTOT;
  int bbase = (bl - l) * 256;              // b*L*256 (elements)
  if (t < 128) {
    // fused softmax over (lev,pt) 16-group: masks 1,2,4,8 stay in-group
    float logit = offattn[(size_t)bl * 384 + 256 + t];
    float mx = logit;
#pragma unroll
    for (int o = 1; o < 16; o <<= 1) mx = fmaxf(mx, __shfl_xor(mx, o));
    float e = __expf(logit - mx);
    float ssum = e;
#pragma unroll
    for (int o = 1; o < 16; o <<= 1) ssum += __shfl_xor(ssum, o);
    float aw = e / ssum;

    int lev = (t >> 2) & 3;
    int lev_q = (l < 64) ? 0 : (l < 320) ? 1 : (l < 1344) ? 2 : 3;
    int start_q = (lev_q == 0) ? 0 : (lev_q == 1) ? 64 : (lev_q == 2) ? 320 : 1344;
    int shq = lev_q + 3;
    int r = l - start_q;
    int Wq = 1 << shq;
    int iy = r >> shq, ix = r & (Wq - 1);
    float invWq = 1.0f / (float)Wq;
    float refx = ((float)ix + 0.5f) * invWq;
    float refy = ((float)iy + 0.5f) * invWq;
    int iW = 8 << lev;
    float Wl = (float)iW;
    int start_l = (lev == 0) ? 0 : (lev == 1) ? 64 : (lev == 2) ? 320 : 1344;
    float ox = offattn[(size_t)bl * 384 + 2 * t];
    float oy = offattn[(size_t)bl * 384 + 2 * t + 1];
    // (ref + off/W)*W - 0.5 == ref*W + off - 0.5
    float gx = refx * Wl + ox - 0.5f;
    float gy = refy * Wl + oy - 0.5f;
    float flx = floorf(gx), fly = floorf(gy);
    int x0 = (int)flx, y0 = (int)fly;
    float fx = gx - flx, fy = gy - fly;
#pragma unroll
    for (int c = 0; c < 4; ++c) {
      int cx = x0 + (c & 1);
      int cy = y0 + (c >> 1);
      int inb = (cx >= 0) && (cx < iW) && (cy >= 0) && (cy < iW);
      int cxc = cx < 0 ? 0 : (cx > iW - 1 ? iW - 1 : cx);
      int cyc = cy < 0 ? 0 : (cy > iW - 1 ? iW - 1 : cy);
      float wx = (c & 1) ? fx : 1.0f - fx;
      float wy = (c & 2) ? fy : 1.0f - fy;
      float wgt = inb ? aw * wx * wy : 0.0f;
      unsigned int idxb = (unsigned int)(start_l + cyc * iW + cxc) * 512u;  // bytes
      sWI[t * 4 + c] = make_uint2(__float_as_uint(wgt), idxb);
    }
  }
  __syncthreads();
  int h = t >> 5, j = t & 31;
  int q = j >> 3, p = j & 7;
  int rotp = ((h & 1) << 2) | q;                 // 8 distinct per wave
  const uint2* wiBase = sWI + h * 64 + q * 16;   // this quarter's 16 slots
  unsigned int chb = (unsigned int)(h * 32 + p * 4) * 2u;  // channel byte off
  const char* vB = (const char*)(vb + bbase);    // wave-uniform base
  f32x2 a01 = {0.0f, 0.0f}, a23 = {0.0f, 0.0f};
#pragma unroll
  for (int kp = 0; kp < 8; ++kp) {
    int kq = ((kp + rotp) & 7) * 2;
    uint4 wi2 = *(const uint4*)(wiBase + kq);    // 2 slots: (w0,i0,w1,i1)
    float w0 = __uint_as_float(wi2.x);
    float w1 = __uint_as_float(wi2.z);
    uint2 u0 = *(const uint2*)(vB + (wi2.y + chb));
    uint2 u1 = *(const uint2*)(vB + (wi2.w + chb));
    f32x2 v01a = { __uint_as_float(u0.x << 16), __uint_as_float(u0.x & 0xffff0000u) };
    f32x2 v23a = { __uint_as_float(u0.y << 16), __uint_as_float(u0.y & 0xffff0000u) };
    f32x2 w0v = {w0, w0};
    a01 = __builtin_elementwise_fma(w0v, v01a, a01);
    a23 = __builtin_elementwise_fma(w0v, v23a, a23);
    f32x2 v01b = { __uint_as_float(u1.x << 16), __uint_as_float(u1.x & 0xffff0000u) };
    f32x2 v23b = { __uint_as_float(u1.y << 16), __uint_as_float(u1.y & 0xffff0000u) };
    f32x2 w1v = {w1, w1};
    a01 = __builtin_elementwise_fma(w1v, v01b, a01);
    a23 = __builtin_elementwise_fma(w1v, v23b, a23);
  }
  float c0 = a01.x, c1 = a01.y, c2 = a23.x, c3 = a23.y;
  c0 += __shfl_xor(c0, 8);  c1 += __shfl_xor(c1, 8);
  c2 += __shfl_xor(c2, 8);  c3 += __shfl_xor(c3, 8);
  c0 += __shfl_xor(c0, 16); c1 += __shfl_xor(c1, 16);
  c2 += __shfl_xor(c2, 16); c3 += __shfl_xor(c3, 16);
  if (q == 0) {
    uint2 pk;
    pk.x = (unsigned int)f2bf(c0) | ((unsigned int)f2bf(c1) << 16);
    pk.y = (unsigned int)f2bf(c2) | ((unsigned int)f2bf(c3) << 16);
    *(uint2*)(samp + (size_t)bl * 256 + h * 32 + p * 4) = pk;
  }
}

// x' = LN(x + y); writes f32 + bf16 shadow; QADD: also qb = bf16(x' + pos + lev_emb)
template<bool QADD>
__global__ __launch_bounds__(256) void ln_fused(
    const float* __restrict__ xin, const float* __restrict__ yin,
    const float* __restrict__ g, const float* __restrict__ bb,
    const float* __restrict__ pos, const float* __restrict__ lev_emb,
    float* __restrict__ xout, unsigned short* __restrict__ xbout,
    unsigned short* __restrict__ qbout) {
  int row = blockIdx.x * 4 + (threadIdx.x >> 6);
  int lane = threadIdx.x & 63;
  size_t base = (size_t)row * 64 + lane;   // float4 units
  float4 xv = ((const float4*)xin)[base];
  float4 yv = ((const float4*)yin)[base];
  float4 tv;
  tv.x = xv.x + yv.x; tv.y = xv.y + yv.y; tv.z = xv.z + yv.z; tv.w = xv.w + yv.w;
  float s = tv.x + tv.y + tv.z + tv.w;
  float s2 = tv.x * tv.x + tv.y * tv.y + tv.z * tv.z + tv.w * tv.w;
#pragma unroll
  for (int o = 1; o < 64; o <<= 1) {
    s += __shfl_xor(s, o, 64);
    s2 += __shfl_xor(s2, o, 64);
  }
  float mean = s * (1.0f / 256.0f);
  float var = s2 * (1.0f / 256.0f) - mean * mean;
  float rstd = rsqrtf(var + 1e-5f);
  float4 gv = ((const float4*)g)[lane];
  float4 bv = ((const float4*)bb)[lane];
  float4 o;
  o.x = gv.x * (tv.x - mean) * rstd + bv.x;
  o.y = gv.y * (tv.y - mean) * rstd + bv.y;
  o.z = gv.z * (tv.z - mean) * rstd + bv.z;
  o.w = gv.w * (tv.w - mean) * rstd + bv.w;
  ((float4*)xout)[base] = o;
  ushort4 ob;
  ob.x = f2bf(o.x); ob.y = f2bf(o.y); ob.z = f2bf(o.z); ob.w = f2bf(o.w);
  ((ushort4*)xbout)[base] = ob;
  if (QADD) {
    int tok = row % LTOT;
    int lev = (tok < 64) ? 0 : (tok < 320) ? 1 : (tok < 1344) ? 2 : 3;
    float4 pv = ((const float4*)pos)[base];
    float4 lv = ((const float4*)lev_emb)[lev * 64 + lane];
    ushort4 q;
    q.x = f2bf(o.x + pv.x + lv.x);
    q.y = f2bf(o.y + pv.y + lv.y);
    q.z = f2bf(o.z + pv.z + lv.z);
    q.w = f2bf(o.w + pv.w + lv.w);
    ((ushort4*)qbout)[base] = q;
  }
}

extern "C" void kernel_launch(void* const* d_in, const int* in_sizes, int n_in,
                              void* d_out, int out_size, void* d_ws, size_t ws_size,
                              hipStream_t stream) {
  (void)in_sizes; (void)n_in; (void)out_size; (void)ws_size;
  const float* src     = (const float*)d_in[0];
  const float* pos     = (const float*)d_in[1];
  const float* lev_emb = (const float*)d_in[2];
  const float* w_off   = (const float*)d_in[3];
  const float* b_off   = (const float*)d_in[4];
  const float* w_attn  = (const float*)d_in[5];
  const float* b_attn  = (const float*)d_in[6];
  const float* w_val   = (const float*)d_in[7];
  const float* b_val   = (const float*)d_in[8];
  const float* w_out   = (const float*)d_in[9];
  const float* b_out   = (const float*)d_in[10];
  const float* ln1_g   = (const float*)d_in[11];
  const float* ln1_b   = (const float*)d_in[12];
  const float* w_ff1   = (const float*)d_in[13];
  const float* b_ff1   = (const float*)d_in[14];
  const float* w_ff2   = (const float*)d_in[15];
  const float* b_ff2   = (const float*)d_in[16];
  const float* ln2_g   = (const float*)d_in[17];
  const float* ln2_b   = (const float*)d_in[18];

  char* ws = (char*)d_ws;
  float*          x     = (float*)(ws + 0);
  float*          y     = (float*)(ws + 22282240);
  unsigned short* xb    = (unsigned short*)(ws + 44564480);
  unsigned short* qb    = (unsigned short*)(ws + 55705600);  // aliased w/ sampb
  unsigned short* sampb = (unsigned short*)(ws + 55705600);  // (disjoint lifetimes)
  float*          offat = (float*)(ws + 66846720);           // [NTOK][384]
  unsigned short* vb    = (unsigned short*)(ws + 100270080);
  unsigned short* h1    = (unsigned short*)(ws + 66846720);  // alias offat+vb
  unsigned short* wT    = (unsigned short*)(ws + 111411200);
  float*          fb    = (float*)(ws + 120455168);          // fused bias [6][384]

  wconv<<<17664, 256, 0, stream>>>(w_off, w_attn, w_val, w_out, w_ff1, w_ff2, wT);
  bpack<<<6, 384, 0, stream>>>(b_off, b_attn, fb);
  prep<<<5440, 256, 0, stream>>>(src, pos, lev_emb, x, xb, qb);

  for (int i = 0; i < 6; ++i) {
    const unsigned short* wl = wT + (size_t)i * 753664;
    gemm_tn<false, false><<<dim3(170, 3), 256, 0, stream>>>(qb, wl + 0,      fb + i * 384,     (void*)offat, NTOK, 384, 256);
    gemm_tn<false, true ><<<dim3(170, 2), 256, 0, stream>>>(xb, wl + 98304,  b_val + i * 256,  (void*)vb,    NTOK, 256, 256);
    ms_sample<<<NTOK, 256, 0, stream>>>(offat, vb, sampb);
    gemm_tn<false, false><<<dim3(170, 2), 256, 0, stream>>>(sampb, wl + 163840, b_out + i * 256, (void*)y,   NTOK, 256, 256);
    ln_fused<false><<<5440, 256, 0, stream>>>(x, y, ln1_g + i * 256, ln1_b + i * 256, pos, lev_emb, x, xb, qb);
    gemm_tn<true,  true ><<<dim3(170, 8), 256, 0, stream>>>(xb, wl + 229376, b_ff1 + i * 1024, (void*)h1,    NTOK, 1024, 256);
    gemm_tn<false, false><<<dim3(170, 2), 256, 0, stream>>>(h1, wl + 491520, b_ff2 + i * 256,  (void*)y,     NTOK, 256, 1024);
    float* xo = (i == 5) ? (float*)d_out : x;
    if (i < 5)
      ln_fused<true ><<<5440, 256, 0, stream>>>(x, y, ln2_g + i * 256, ln2_b + i * 256, pos, lev_emb, xo, xb, qb);
    else
      ln_fused<false><<<5440, 256, 0, stream>>>(x, y, ln2_g + i * 256, ln2_b + i * 256, pos, lev_emb, xo, xb, qb);
  }
}